// Round 9
// baseline (392.304 us; speedup 1.0000x reference)
//
#include <hip/hip_runtime.h>
#include <hip/hip_cooperative_groups.h>

namespace cg = cooperative_groups;

#define NN 100000
#define NE 1200000
#define DD 64
#define NTILES 3125        // NN/32 exact
#define NBK 391            // buckets, 256 rows each (row>>8)
#define EPB 4688           // ceil(NE/256) edges per chunk (256 chunks)

typedef unsigned int uint32;
typedef unsigned char uint8;
typedef unsigned short ushort16;
typedef __attribute__((ext_vector_type(8))) short short8;    // 8 bf16 (4 VGPR)
typedef __attribute__((ext_vector_type(16))) float f32x16;   // MFMA 32x32 acc

__device__ __forceinline__ ushort16 f2bf(float x) {
    uint32 u = __float_as_uint(x);
    u += 0x7FFFu + ((u >> 16) & 1u);   // round-to-nearest-even
    return (ushort16)(u >> 16);
}
__device__ __forceinline__ float bflo(uint32 u) { return __uint_as_float(u << 16); }
__device__ __forceinline__ float bfhi(uint32 u) { return __uint_as_float(u & 0xFFFF0000u); }
__device__ __forceinline__ uint32 pack2(float a, float b) {
    return (uint32)f2bf(a) | ((uint32)f2bf(b) << 16);
}
__device__ __forceinline__ int wave_incl_scan(int v) {
    #pragma unroll
    for (int d = 1; d < 64; d <<= 1) {
        int u = __shfl_up(v, d);
        if ((int)(threadIdx.x & 63) >= d) v += u;
    }
    return v;
}

// ---- Cooperative fused CSR build (+ W pre-pack) -------------------------
// Phase 0: packW. A: chunk bucket-count -> M[bucket][chunk]. B: per-bucket
// wave-scan of M row -> Mscan, totals. C: redundant wave-scan of totals ->
// LDS partials; chunk scatter into bucket order (LDS cursors). D: per-bucket
// row-hist + wave-scan -> offsets; LDS-cursor scatter -> final edges.

__global__ __launch_bounds__(512)
void k_csr(const int* __restrict__ row, const int* __restrict__ col,
           const float* __restrict__ ew,
           const float* __restrict__ selfk, const float* __restrict__ neighk,
           short8* __restrict__ wpack,
           int* __restrict__ M, int* __restrict__ totals, int* __restrict__ Mscan,
           uint32* __restrict__ colw, uint8* __restrict__ rowlo,
           uint32* __restrict__ edges, int* __restrict__ offsets) {
    cg::grid_group grid = cg::this_grid();
    __shared__ int sBins[NBK];   // A: bins, C: cursors, D: bins->cursors
    __shared__ int sPart[NBK];   // bucket-start partials (C..D)
    __shared__ int sB2[256];     // D: row bases
    int b = blockIdx.x;          // 0..390
    int t = threadIdx.x;         // 0..511
    int lane = t & 63;

    // phase 0: packW (first 3072 global threads)
    {
        int tid = b * 512 + t;
        if (tid < 3 * 16 * 64) {
            int wl    = tid & 63;
            int frag  = (tid >> 6) & 15;
            int layer = tid >> 10;
            int g = frag >> 3, th = (frag >> 2) & 1, s = frag & 3;
            const float* W = (g ? neighk : selfk) + layer * 4096;
            int n = th * 32 + (wl & 31);
            int k0 = s * 16 + (wl >> 5) * 8;
            short8 v;
            #pragma unroll
            for (int j = 0; j < 8; j++) v[j] = (short)f2bf(W[(k0 + j) * 64 + n]);
            wpack[tid] = v;
        }
    }

    // phase A: bucket count per chunk (chunks = blocks 0..255)
    for (int i = t; i < NBK; i += 512) sBins[i] = 0;
    __syncthreads();
    if (b < 256) {
        int start = b * EPB, end = min(start + EPB, NE);
        for (int e = start + t; e < end; e += 512)
            atomicAdd(&sBins[row[e] >> 8], 1);
        __syncthreads();
        for (int i = t; i < NBK; i += 512) M[i * 256 + b] = sBins[i];
    }
    grid.sync();

    // phase B: per-bucket exclusive scan over chunks (wave 0 of each block)
    if (t < 64) {
        int carry = 0;
        #pragma unroll
        for (int c = 0; c < 4; c++) {
            int v = M[b * 256 + c * 64 + lane];
            int incl = wave_incl_scan(v);
            Mscan[b * 256 + c * 64 + lane] = carry + incl - v;
            carry += __shfl(incl, 63);
        }
        if (lane == 0) totals[b] = carry;
    }
    grid.sync();

    // phase C: redundant exclusive scan of totals -> sPart; chunk scatter
    if (t < 64) {
        int carry = 0;
        #pragma unroll
        for (int c = 0; c < 7; c++) {          // 7*64 = 448 >= NBK
            int idx = c * 64 + lane;
            int v = (idx < NBK) ? totals[idx] : 0;
            int incl = wave_incl_scan(v);
            if (idx < NBK) sPart[idx] = carry + incl - v;
            carry += __shfl(incl, 63);
        }
    }
    __syncthreads();
    if (b < 256) {
        for (int i = t; i < NBK; i += 512) sBins[i] = Mscan[i * 256 + b] + sPart[i];
        __syncthreads();
        int start = b * EPB, end = min(start + EPB, NE);
        for (int e = start + t; e < end; e += 512) {
            int r = row[e];
            int wq = (int)(ew[e] * 32767.0f + 0.5f);
            wq = (wq > 32767) ? 32767 : wq;
            int p = atomicAdd(&sBins[r >> 8], 1);
            colw[p]  = ((uint32)col[e] << 15) | (uint32)wq;
            rowlo[p] = (uint8)(r & 255);
        }
    }
    grid.sync();

    // phase D: build bucket b
    int bstart = sPart[b];
    int bend   = bstart + totals[b];
    if (t < 256) sBins[t] = 0;
    __syncthreads();
    for (int p = bstart + t; p < bend; p += 512)
        atomicAdd(&sBins[rowlo[p]], 1);
    __syncthreads();
    if (t < 64) {
        int carry = 0;
        #pragma unroll
        for (int c = 0; c < 4; c++) {
            int v = sBins[c * 64 + lane];
            int incl = wave_incl_scan(v);
            sB2[c * 64 + lane] = bstart + carry + incl - v;
            carry += __shfl(incl, 63);
        }
    }
    __syncthreads();
    if (t < 256) {
        int rowid = b * 256 + t;
        if (rowid < NN) offsets[rowid] = sB2[t];
        sBins[t] = sB2[t];                      // cursors
    }
    if (b == 0 && t == 0) offsets[NN] = NE;
    __syncthreads();
    for (int p = bstart + t; p < bend; p += 512) {
        uint32 cw = colw[p];
        int dst = atomicAdd(&sBins[rowlo[p]], 1);
        edges[dst] = cw;                        // block-private range: full lines
    }
}

// ---- MFMA GEMM (layer 1 only): hs = x@Ws + b, y = x@Wn ------------------

__global__ __launch_bounds__(256)
void gemm_mfma(const float* __restrict__ hf_, ushort16* __restrict__ hs,
               ushort16* __restrict__ y,
               const short8* __restrict__ wpack,
               const float* __restrict__ bias) {
    int lane  = threadIdx.x & 63;
    int wave  = threadIdx.x >> 6;
    int wid   = blockIdx.x * 4 + wave;
    int nwv   = gridDim.x * 4;
    int mrow  = lane & 31;
    int khalf = lane >> 5;
    int t     = wid & 1;

    short8 Wf[2][4];
    #pragma unroll
    for (int g = 0; g < 2; g++)
        #pragma unroll
        for (int s = 0; s < 4; s++)
            Wf[g][s] = wpack[(((g * 2 + t) * 4) + s) * 64 + lane];

    float bval = bias[t * 32 + mrow];

    for (int tile = wid >> 1; tile < NTILES; tile += nwv >> 1) {
        int n0 = tile * 32;
        const float* hf = hf_ + (n0 + mrow) * 64 + khalf * 8;
        short8 A[4];
        #pragma unroll
        for (int s = 0; s < 4; s++) {
            short8 a;
            #pragma unroll
            for (int j = 0; j < 8; j++) a[j] = (short)f2bf(hf[s * 16 + j]);
            A[s] = a;
        }

        f32x16 acc0, acc1;
        #pragma unroll
        for (int r = 0; r < 16; r++) { acc0[r] = 0.f; acc1[r] = 0.f; }

        #pragma unroll
        for (int s = 0; s < 4; s++) {
            acc0 = __builtin_amdgcn_mfma_f32_32x32x16_bf16(A[s], Wf[0][s], acc0, 0, 0, 0);
            acc1 = __builtin_amdgcn_mfma_f32_32x32x16_bf16(A[s], Wf[1][s], acc1, 0, 0, 0);
        }

        int colbase = t * 32 + mrow;
        #pragma unroll
        for (int r = 0; r < 16; r++) {
            int rw = (r & 3) + 8 * (r >> 2) + 4 * khalf;
            int n = n0 + rw;
            hs[n * DD + colbase] = f2bf(acc0[r] + bval);
            y [n * DD + colbase] = f2bf(acc1[r]);
        }
    }
}

// ---- Fused agg + next-layer GEMM ---------------------------------------

__global__ __launch_bounds__(256)
void agg_gemm(const uint2* __restrict__ hs2, const uint2* __restrict__ y2,
              ushort16* __restrict__ hs_out, ushort16* __restrict__ y_out,
              const int* __restrict__ offsets, const uint32* __restrict__ edges,
              const short8* __restrict__ wpack, const float* __restrict__ bias) {
    __shared__ uint32 sh[32 * 36];
    int lane = threadIdx.x & 63;
    int wave = threadIdx.x >> 6;
    int g  = lane >> 4;          // group 0..3
    int fl = lane & 15;          // feature quad
    int n0 = blockIdx.x * 32;

    #pragma unroll
    for (int q = 0; q < 2; q++) {
        int lrow = wave * 8 + q * 4 + g;     // 0..31
        int n = n0 + lrow;
        uint2 hv = hs2[n * 16 + fl];
        float a0 = bflo(hv.x), a1 = bfhi(hv.x), a2 = bflo(hv.y), a3 = bfhi(hv.y);
        int s = offsets[n], e = offsets[n + 1];
        #pragma unroll 4
        for (int j = s; j < e; j++) {
            uint32 ed = edges[j];
            int c = (int)(ed >> 15);
            float w = (float)(ed & 32767u) * (1.0f / 32767.0f);
            uint2 yv = y2[c * 16 + fl];
            a0 = fmaf(bflo(yv.x), w, a0);
            a1 = fmaf(bfhi(yv.x), w, a1);
            a2 = fmaf(bflo(yv.y), w, a2);
            a3 = fmaf(bfhi(yv.y), w, a3);
        }
        sh[lrow * 36 + fl * 2]     = pack2(fmaxf(a0, 0.f), fmaxf(a1, 0.f));
        sh[lrow * 36 + fl * 2 + 1] = pack2(fmaxf(a2, 0.f), fmaxf(a3, 0.f));
    }
    __syncthreads();

    // gemm phase
    int mrow  = lane & 31;
    int khalf = lane >> 5;
    int gsel  = wave >> 1;       // 0=self(hs) 1=neigh(y)
    int t     = wave & 1;        // col half

    short8 Wf[4];
    #pragma unroll
    for (int s = 0; s < 4; s++)
        Wf[s] = wpack[(((gsel * 2 + t) * 4) + s) * 64 + lane];

    short8 A[4];
    #pragma unroll
    for (int s = 0; s < 4; s++)
        A[s] = *(const short8*)&sh[mrow * 36 + s * 8 + khalf * 4];   // 16B, aligned

    f32x16 acc;
    #pragma unroll
    for (int r = 0; r < 16; r++) acc[r] = 0.f;
    #pragma unroll
    for (int s = 0; s < 4; s++)
        acc = __builtin_amdgcn_mfma_f32_32x32x16_bf16(A[s], Wf[s], acc, 0, 0, 0);

    float bval = gsel ? 0.f : bias[t * 32 + mrow];
    ushort16* dst = gsel ? y_out : hs_out;
    int colbase = t * 32 + mrow;
    #pragma unroll
    for (int r = 0; r < 16; r++) {
        int rw = (r & 3) + 8 * (r >> 2) + 4 * khalf;
        int n = n0 + rw;
        dst[n * DD + colbase] = f2bf(acc[r] + bval);
    }
}

// ---- Final aggregate: out = relu(hs[n] + sum_j w_j * y[col_j]), f32 ----

__global__ __launch_bounds__(256)
void agg_final(const uint2* __restrict__ hs2, const uint2* __restrict__ y2,
               float4* __restrict__ out, const int* __restrict__ offsets,
               const uint32* __restrict__ edges) {
    int lane = threadIdx.x & 63;
    int wave = threadIdx.x >> 6;
    int g  = lane >> 4;
    int fl = lane & 15;
    int n = (blockIdx.x * 4 + wave) * 4 + g;   // 6250*16 == NN exact

    uint2 hv = hs2[n * 16 + fl];
    float a0 = bflo(hv.x), a1 = bfhi(hv.x), a2 = bflo(hv.y), a3 = bfhi(hv.y);

    int s = offsets[n], e = offsets[n + 1];
    #pragma unroll 4
    for (int j = s; j < e; j++) {
        uint32 ed = edges[j];
        int c = (int)(ed >> 15);
        float w = (float)(ed & 32767u) * (1.0f / 32767.0f);
        uint2 yv = y2[c * 16 + fl];
        a0 = fmaf(bflo(yv.x), w, a0);
        a1 = fmaf(bfhi(yv.x), w, a1);
        a2 = fmaf(bflo(yv.y), w, a2);
        a3 = fmaf(bfhi(yv.y), w, a3);
    }
    out[n * 16 + fl] = make_float4(fmaxf(a0, 0.f), fmaxf(a1, 0.f),
                                   fmaxf(a2, 0.f), fmaxf(a3, 0.f));
}

// ---- launch -------------------------------------------------------------

extern "C" void kernel_launch(void* const* d_in, const int* in_sizes, int n_in,
                              void* d_out, int out_size, void* d_ws, size_t ws_size,
                              hipStream_t stream) {
    const float* x      = (const float*)d_in[0];
    const int*   ei     = (const int*)d_in[1];
    const float* ew     = (const float*)d_in[2];
    const float* selfk  = (const float*)d_in[3];
    const float* neighk = (const float*)d_in[4];
    const float* biases = (const float*)d_in[5];
    float* out = (float*)d_out;

    char* w = (char*)d_ws;
    ushort16* hsA   = (ushort16*)w; w += (size_t)NN * DD * sizeof(ushort16);
    ushort16* yA    = (ushort16*)w; w += (size_t)NN * DD * sizeof(ushort16);
    ushort16* hsB   = (ushort16*)w; w += (size_t)NN * DD * sizeof(ushort16);
    ushort16* yB    = (ushort16*)w; w += (size_t)NN * DD * sizeof(ushort16);
    uint32* edges   = (uint32*)w;   w += (size_t)NE * sizeof(uint32);
    uint32* colwB   = (uint32*)w;   w += (size_t)NE * sizeof(uint32);
    uint8*  rowlo   = (uint8*)w;    w += (size_t)NE * sizeof(uint8);
    w = (char*)(((size_t)w + 255) & ~(size_t)255);
    int*    M       = (int*)w;      w += (size_t)NBK * 256 * sizeof(int);
    int*    Mscan   = (int*)w;      w += (size_t)NBK * 256 * sizeof(int);
    int*    offsets = (int*)w;      w += (size_t)(NN + 1) * sizeof(int);
    int*    totals  = (int*)w;      w += 512 * sizeof(int);
    short8* wpack   = (short8*)w;   w += (size_t)3 * 16 * 64 * sizeof(short8);

    const int* row = ei;
    const int* col = ei + NE;

    void* args[] = {(void*)&row, (void*)&col, (void*)&ew,
                    (void*)&selfk, (void*)&neighk, (void*)&wpack,
                    (void*)&M, (void*)&totals, (void*)&Mscan,
                    (void*)&colwB, (void*)&rowlo, (void*)&edges, (void*)&offsets};
    hipLaunchCooperativeKernel((const void*)k_csr, dim3(NBK), dim3(512),
                               args, 0, stream);

    // layer 1 GEMM: x (f32) -> hsA, yA
    gemm_mfma<<<782, 256, 0, stream>>>(x, hsA, yA, wpack, biases);
    // agg(layer1) + GEMM(layer2): -> hsB, yB
    agg_gemm <<<NTILES, 256, 0, stream>>>((const uint2*)hsA, (const uint2*)yA,
                                          hsB, yB, offsets, edges,
                                          wpack + 1024, biases + 64);
    // agg(layer2) + GEMM(layer3): -> hsA, yA
    agg_gemm <<<NTILES, 256, 0, stream>>>((const uint2*)hsB, (const uint2*)yB,
                                          hsA, yA, offsets, edges,
                                          wpack + 2048, biases + 128);
    // final aggregate -> out (f32)
    agg_final<<<NN / 16, 256, 0, stream>>>((const uint2*)hsA, (const uint2*)yA,
                                           (float4*)out, offsets, edges);
}

// Round 10
// 250.039 us; speedup vs baseline: 1.5690x; 1.5690x over previous
//
#include <hip/hip_runtime.h>

#define NN 100000
#define NE 1200000
#define DD 64
#define NTILES 3125        // NN/32 exact
#define NBK 391            // buckets, 256 rows each (row>>8); NBK*256 = 100096
#define MLEN (NBK * 256)   // count-matrix length
#define EPB 4688           // ceil(NE/256) edges per bucket-pass block
#define GEMM_BLOCKS 782    // 3128 waves -> 6250 wave-jobs, ~2 tiles/wave

typedef unsigned int uint32;
typedef unsigned char uint8;
typedef unsigned short ushort16;
typedef __attribute__((ext_vector_type(8))) short short8;    // 8 bf16 (4 VGPR)
typedef __attribute__((ext_vector_type(16))) float f32x16;   // MFMA 32x32 acc

__device__ __forceinline__ ushort16 f2bf(float x) {
    uint32 u = __float_as_uint(x);
    u += 0x7FFFu + ((u >> 16) & 1u);   // round-to-nearest-even
    return (ushort16)(u >> 16);
}
__device__ __forceinline__ float bflo(uint32 u) { return __uint_as_float(u << 16); }
__device__ __forceinline__ float bfhi(uint32 u) { return __uint_as_float(u & 0xFFFF0000u); }
__device__ __forceinline__ uint32 pack2(float a, float b) {
    return (uint32)f2bf(a) | ((uint32)f2bf(b) << 16);
}

// inline W-fragment pack: frag (s) for fixed (matrix W, col-half t), lane
// decomposed as mrow=lane&31, khalf=lane>>5 (matches MFMA B-operand layout)
__device__ __forceinline__ short8 packWfrag(const float* __restrict__ W,
                                            int s, int t, int mrow, int khalf) {
    short8 v;
    const float* p = W + (s * 16 + khalf * 8) * 64 + t * 32 + mrow;
    #pragma unroll
    for (int j = 0; j < 8; j++) v[j] = (short)f2bf(p[j * 64]);
    return v;
}

// ---- Merged: layer-1 GEMM (blocks 256..1037) + bucket count (0..255) ----

__global__ __launch_bounds__(256)
void k_gemm_bcount(const float* __restrict__ x,
                   ushort16* __restrict__ hs, ushort16* __restrict__ y,
                   const float* __restrict__ selfk, const float* __restrict__ neighk,
                   const float* __restrict__ bias,
                   const int* __restrict__ row, int* __restrict__ M) {
    __shared__ int bins[NBK];
    int t = threadIdx.x;
    if (blockIdx.x < 256) {
        // ---- bucket count ----
        int b = blockIdx.x;
        for (int i = t; i < NBK; i += 256) bins[i] = 0;
        __syncthreads();
        int start = b * EPB, end = min(start + EPB, NE);
        for (int e = start + t; e < end; e += 256)
            atomicAdd(&bins[row[e] >> 8], 1);
        __syncthreads();
        for (int i = t; i < NBK; i += 256) M[i * 256 + b] = bins[i];
        return;
    }
    // ---- layer-1 GEMM: hs = x@Ws + b, y = x@Wn ----
    int lane  = t & 63;
    int wave  = t >> 6;
    int wid   = (blockIdx.x - 256) * 4 + wave;
    int mrow  = lane & 31;
    int khalf = lane >> 5;
    int th    = wid & 1;

    short8 Wf[2][4];
    #pragma unroll
    for (int s = 0; s < 4; s++) {
        Wf[0][s] = packWfrag(selfk,  s, th, mrow, khalf);
        Wf[1][s] = packWfrag(neighk, s, th, mrow, khalf);
    }
    float bval = bias[th * 32 + mrow];

    for (int tile = wid >> 1; tile < NTILES; tile += (GEMM_BLOCKS * 4) >> 1) {
        int n0 = tile * 32;
        const float* hf = x + (n0 + mrow) * 64 + khalf * 8;
        short8 A[4];
        #pragma unroll
        for (int s = 0; s < 4; s++) {
            short8 a;
            #pragma unroll
            for (int j = 0; j < 8; j++) a[j] = (short)f2bf(hf[s * 16 + j]);
            A[s] = a;
        }

        f32x16 acc0, acc1;
        #pragma unroll
        for (int r = 0; r < 16; r++) { acc0[r] = 0.f; acc1[r] = 0.f; }
        #pragma unroll
        for (int s = 0; s < 4; s++) {
            acc0 = __builtin_amdgcn_mfma_f32_32x32x16_bf16(A[s], Wf[0][s], acc0, 0, 0, 0);
            acc1 = __builtin_amdgcn_mfma_f32_32x32x16_bf16(A[s], Wf[1][s], acc1, 0, 0, 0);
        }

        int colbase = th * 32 + mrow;
        #pragma unroll
        for (int r = 0; r < 16; r++) {
            int rw = (r & 3) + 8 * (r >> 2) + 4 * khalf;
            int n = n0 + rw;
            hs[n * DD + colbase] = f2bf(acc0[r] + bval);
            y [n * DD + colbase] = f2bf(acc1[r]);
        }
    }
}

// ---- CSR build (split kernels, proven R8 path) --------------------------

__global__ void k_scan1(const int* __restrict__ in, int* __restrict__ outx,
                        int* __restrict__ partials) {
    __shared__ int tmp[256];
    int t = threadIdx.x;
    int i = blockIdx.x * 256 + t;
    int v = (i < MLEN) ? in[i] : 0;
    tmp[t] = v;
    __syncthreads();
    #pragma unroll
    for (int off = 1; off < 256; off <<= 1) {
        int add = (t >= off) ? tmp[t - off] : 0;
        __syncthreads();
        tmp[t] += add;
        __syncthreads();
    }
    if (i < MLEN) outx[i] = tmp[t] - v;            // exclusive (within block)
    if (t == 255) partials[blockIdx.x] = tmp[255]; // block total
}

__global__ void k_scan2(int* __restrict__ partials) {
    __shared__ int tmp[512];
    int t = threadIdx.x;
    int v = (t < NBK) ? partials[t] : 0;
    tmp[t] = v;
    __syncthreads();
    #pragma unroll
    for (int off = 1; off < 512; off <<= 1) {
        int add = (t >= off) ? tmp[t - off] : 0;
        __syncthreads();
        tmp[t] += add;
        __syncthreads();
    }
    if (t < NBK) partials[t] = tmp[t] - v;         // exclusive
}

__global__ __launch_bounds__(512)
void k_bscatter(const int* __restrict__ row, const int* __restrict__ col,
                const float* __restrict__ ew, const int* __restrict__ Mscan,
                const int* __restrict__ partials,
                uint32* __restrict__ colw, uint8* __restrict__ rowlo) {
    __shared__ int cur[NBK];
    for (int i = threadIdx.x; i < NBK; i += 512)
        cur[i] = Mscan[i * 256 + blockIdx.x] + partials[i];
    __syncthreads();
    int start = blockIdx.x * EPB;
    int end = min(start + EPB, NE);
    for (int e = start + (int)threadIdx.x; e < end; e += 512) {
        int r = row[e];
        int wq = (int)(ew[e] * 32767.0f + 0.5f);
        wq = (wq > 32767) ? 32767 : wq;
        int p = atomicAdd(&cur[r >> 8], 1);
        colw[p]  = ((uint32)col[e] << 15) | (uint32)wq;
        rowlo[p] = (uint8)(r & 255);
    }
}

__global__ __launch_bounds__(256)
void k_build(const int* __restrict__ Mscan, const int* __restrict__ partials,
             const uint32* __restrict__ colw, const uint8* __restrict__ rowlo,
             uint32* __restrict__ edges, int* __restrict__ offsets) {
    __shared__ int bins[256];
    __shared__ int tmp[256];
    __shared__ int cur[256];
    int b = blockIdx.x;
    int t = threadIdx.x;
    int bstart = Mscan[b * 256] + partials[b];
    int bend   = (b == NBK - 1) ? NE : Mscan[(b + 1) * 256] + partials[b + 1];
    bins[t] = 0;
    __syncthreads();
    for (int p = bstart + t; p < bend; p += 256)
        atomicAdd(&bins[rowlo[p]], 1);
    __syncthreads();
    int v = bins[t];
    tmp[t] = v;
    __syncthreads();
    #pragma unroll
    for (int off = 1; off < 256; off <<= 1) {
        int add = (t >= off) ? tmp[t - off] : 0;
        __syncthreads();
        tmp[t] += add;
        __syncthreads();
    }
    int base = bstart + (tmp[t] - v);
    cur[t] = base;
    int rowid = b * 256 + t;
    if (rowid < NN) offsets[rowid] = base;
    if (b == 0 && t == 0) offsets[NN] = NE;
    __syncthreads();
    for (int p = bstart + t; p < bend; p += 256) {
        uint32 cw = colw[p];
        int dst = atomicAdd(&cur[rowlo[p]], 1);
        edges[dst] = cw;                 // block-private range: full lines
    }
}

// ---- Fused agg + next-layer GEMM ---------------------------------------
// Block = 32 nodes. Agg phase: 4 waves x 8 nodes (16-lane group per node,
// lane owns 4 feats, uint2 gather). h packed bf16 into LDS (stride 36 uints
// = 144 B to break the 128 B bank alias). Gemm phase: wave = gsel*2 + t.

__global__ __launch_bounds__(256)
void agg_gemm(const uint2* __restrict__ hs2, const uint2* __restrict__ y2,
              ushort16* __restrict__ hs_out, ushort16* __restrict__ y_out,
              const int* __restrict__ offsets, const uint32* __restrict__ edges,
              const float* __restrict__ selfk, const float* __restrict__ neighk,
              const float* __restrict__ bias) {
    __shared__ uint32 sh[32 * 36];
    int lane = threadIdx.x & 63;
    int wave = threadIdx.x >> 6;
    int g  = lane >> 4;          // group 0..3
    int fl = lane & 15;          // feature quad
    int n0 = blockIdx.x * 32;

    // W fragments for this wave's (matrix, col-half) — inline pack, L2-hot
    int mrow  = lane & 31;
    int khalf = lane >> 5;
    int gsel  = wave >> 1;       // 0=self(hs) 1=neigh(y)
    int t     = wave & 1;        // col half
    const float* W = gsel ? neighk : selfk;
    short8 Wf[4];
    #pragma unroll
    for (int s = 0; s < 4; s++) Wf[s] = packWfrag(W, s, t, mrow, khalf);

    #pragma unroll
    for (int q = 0; q < 2; q++) {
        int lrow = wave * 8 + q * 4 + g;     // 0..31
        int n = n0 + lrow;
        uint2 hv = hs2[n * 16 + fl];
        float a0 = bflo(hv.x), a1 = bfhi(hv.x), a2 = bflo(hv.y), a3 = bfhi(hv.y);
        int s = offsets[n], e = offsets[n + 1];
        #pragma unroll 4
        for (int j = s; j < e; j++) {
            uint32 ed = edges[j];
            int c = (int)(ed >> 15);
            float w = (float)(ed & 32767u) * (1.0f / 32767.0f);
            uint2 yv = y2[c * 16 + fl];
            a0 = fmaf(bflo(yv.x), w, a0);
            a1 = fmaf(bfhi(yv.x), w, a1);
            a2 = fmaf(bflo(yv.y), w, a2);
            a3 = fmaf(bfhi(yv.y), w, a3);
        }
        sh[lrow * 36 + fl * 2]     = pack2(fmaxf(a0, 0.f), fmaxf(a1, 0.f));
        sh[lrow * 36 + fl * 2 + 1] = pack2(fmaxf(a2, 0.f), fmaxf(a3, 0.f));
    }
    __syncthreads();

    // gemm phase
    short8 A[4];
    #pragma unroll
    for (int s = 0; s < 4; s++)
        A[s] = *(const short8*)&sh[mrow * 36 + s * 8 + khalf * 4];   // 16B, aligned

    f32x16 acc;
    #pragma unroll
    for (int r = 0; r < 16; r++) acc[r] = 0.f;
    #pragma unroll
    for (int s = 0; s < 4; s++)
        acc = __builtin_amdgcn_mfma_f32_32x32x16_bf16(A[s], Wf[s], acc, 0, 0, 0);

    float bval = gsel ? 0.f : bias[t * 32 + mrow];
    ushort16* dst = gsel ? y_out : hs_out;
    int colbase = t * 32 + mrow;
    #pragma unroll
    for (int r = 0; r < 16; r++) {
        int rw = (r & 3) + 8 * (r >> 2) + 4 * khalf;
        int n = n0 + rw;
        dst[n * DD + colbase] = f2bf(acc[r] + bval);
    }
}

// ---- Final aggregate: out = relu(hs[n] + sum_j w_j * y[col_j]), f32 ----

__global__ __launch_bounds__(256)
void agg_final(const uint2* __restrict__ hs2, const uint2* __restrict__ y2,
               float4* __restrict__ out, const int* __restrict__ offsets,
               const uint32* __restrict__ edges) {
    int lane = threadIdx.x & 63;
    int wave = threadIdx.x >> 6;
    int g  = lane >> 4;
    int fl = lane & 15;
    int n = (blockIdx.x * 4 + wave) * 4 + g;   // 6250*16 == NN exact

    uint2 hv = hs2[n * 16 + fl];
    float a0 = bflo(hv.x), a1 = bfhi(hv.x), a2 = bflo(hv.y), a3 = bfhi(hv.y);

    int s = offsets[n], e = offsets[n + 1];
    #pragma unroll 4
    for (int j = s; j < e; j++) {
        uint32 ed = edges[j];
        int c = (int)(ed >> 15);
        float w = (float)(ed & 32767u) * (1.0f / 32767.0f);
        uint2 yv = y2[c * 16 + fl];
        a0 = fmaf(bflo(yv.x), w, a0);
        a1 = fmaf(bfhi(yv.x), w, a1);
        a2 = fmaf(bflo(yv.y), w, a2);
        a3 = fmaf(bfhi(yv.y), w, a3);
    }
    out[n * 16 + fl] = make_float4(fmaxf(a0, 0.f), fmaxf(a1, 0.f),
                                   fmaxf(a2, 0.f), fmaxf(a3, 0.f));
}

// ---- launch -------------------------------------------------------------

extern "C" void kernel_launch(void* const* d_in, const int* in_sizes, int n_in,
                              void* d_out, int out_size, void* d_ws, size_t ws_size,
                              hipStream_t stream) {
    const float* x      = (const float*)d_in[0];
    const int*   ei     = (const int*)d_in[1];
    const float* ew     = (const float*)d_in[2];
    const float* selfk  = (const float*)d_in[3];
    const float* neighk = (const float*)d_in[4];
    const float* biases = (const float*)d_in[5];
    float* out = (float*)d_out;

    char* w = (char*)d_ws;
    ushort16* hsA   = (ushort16*)w; w += (size_t)NN * DD * sizeof(ushort16);
    ushort16* yA    = (ushort16*)w; w += (size_t)NN * DD * sizeof(ushort16);
    ushort16* hsB   = (ushort16*)w; w += (size_t)NN * DD * sizeof(ushort16);
    ushort16* yB    = (ushort16*)w; w += (size_t)NN * DD * sizeof(ushort16);
    uint32* edges   = (uint32*)w;   w += (size_t)NE * sizeof(uint32);
    uint32* colwB   = (uint32*)w;   w += (size_t)NE * sizeof(uint32);
    uint8*  rowlo   = (uint8*)w;    w += (size_t)NE * sizeof(uint8);
    w = (char*)(((size_t)w + 255) & ~(size_t)255);
    int*    M       = (int*)w;      w += (size_t)MLEN * sizeof(int);
    int*    Mscan   = (int*)w;      w += (size_t)MLEN * sizeof(int);
    int*    offsets = (int*)w;      w += (size_t)(NN + 1) * sizeof(int);
    int*    partials= (int*)w;      w += 512 * sizeof(int);

    const int* row = ei;
    const int* col = ei + NE;

    // layer-1 GEMM + bucket count, one dispatch (independent work)
    k_gemm_bcount<<<256 + GEMM_BLOCKS, 256, 0, stream>>>(x, hsA, yA, selfk, neighk,
                                                         biases, row, M);
    k_scan1   <<<NBK, 256, 0, stream>>>(M, Mscan, partials);
    k_scan2   <<<1, 512, 0, stream>>>(partials);
    k_bscatter<<<256, 512, 0, stream>>>(row, col, ew, Mscan, partials, colwB, rowlo);
    k_build   <<<NBK, 256, 0, stream>>>(Mscan, partials, colwB, rowlo, edges, offsets);

    // agg(layer1) + GEMM(layer2): -> hsB, yB
    agg_gemm <<<NTILES, 256, 0, stream>>>((const uint2*)hsA, (const uint2*)yA,
                                          hsB, yB, offsets, edges,
                                          selfk + 4096, neighk + 4096, biases + 64);
    // agg(layer2) + GEMM(layer3): -> hsA, yA
    agg_gemm <<<NTILES, 256, 0, stream>>>((const uint2*)hsB, (const uint2*)yB,
                                          hsA, yA, offsets, edges,
                                          selfk + 2 * 4096, neighk + 2 * 4096, biases + 128);
    // final aggregate -> out (f32)
    agg_final<<<NN / 16, 256, 0, stream>>>((const uint2*)hsA, (const uint2*)yA,
                                           (float4*)out, offsets, edges);
}

// Round 11
// 238.308 us; speedup vs baseline: 1.6462x; 1.0492x over previous
//
#include <hip/hip_runtime.h>

#define NN 100000
#define NE 1200000
#define DD 64
#define NTILES 3125        // NN/32 exact
#define NBK 391            // buckets, 256 rows each (row>>8); NBK*256 = 100096
#define MLEN (NBK * 256)   // count-matrix length
#define EPB 4688           // ceil(NE/256) edges per bucket-pass block

typedef unsigned int uint32;
typedef unsigned char uint8;
typedef unsigned short ushort16;
typedef __attribute__((ext_vector_type(8))) short short8;    // 8 bf16 (4 VGPR)
typedef __attribute__((ext_vector_type(16))) float f32x16;   // MFMA 32x32 acc

__device__ __forceinline__ ushort16 f2bf(float x) {
    uint32 u = __float_as_uint(x);
    u += 0x7FFFu + ((u >> 16) & 1u);   // round-to-nearest-even
    return (ushort16)(u >> 16);
}
__device__ __forceinline__ float bflo(uint32 u) { return __uint_as_float(u << 16); }
__device__ __forceinline__ float bfhi(uint32 u) { return __uint_as_float(u & 0xFFFF0000u); }
__device__ __forceinline__ uint32 pack2(float a, float b) {
    return (uint32)f2bf(a) | ((uint32)f2bf(b) << 16);
}

// ---- decoupled gather loop: 16 edge words loaded in one coalesced op, ---
// ---- then 16 independent y-gathers in flight. ed=0 padding -> w=0. ------
__device__ __forceinline__ void agg_edges(float& a0, float& a1, float& a2, float& a3,
                                          int s, int e, int gb, int fl,
                                          const uint32* __restrict__ edges,
                                          const uint2* __restrict__ y2) {
    for (int j = s; j < e; j += 16) {
        int idx = j + fl;
        uint32 edw = (idx < e) ? edges[idx] : 0u;   // one 64B load per group
        #pragma unroll
        for (int k = 0; k < 16; k++) {
            uint32 ed = __shfl(edw, gb + k);        // broadcast edge k
            int c = (int)(ed >> 15);                // pad: c=0
            float w = (float)(ed & 32767u) * (1.0f / 32767.0f);  // pad: w=0
            uint2 yv = y2[c * 16 + fl];
            a0 = fmaf(bflo(yv.x), w, a0);
            a1 = fmaf(bfhi(yv.x), w, a1);
            a2 = fmaf(bflo(yv.y), w, a2);
            a3 = fmaf(bfhi(yv.y), w, a3);
        }
    }
}

// ---- CSR build via bucket sort (R8-proven) ------------------------------

__global__ __launch_bounds__(512)
void k_bcount(const int* __restrict__ row, int* __restrict__ M) {
    __shared__ int bins[NBK];
    for (int i = threadIdx.x; i < NBK; i += 512) bins[i] = 0;
    __syncthreads();
    int start = blockIdx.x * EPB;
    int end = min(start + EPB, NE);
    for (int e = start + (int)threadIdx.x; e < end; e += 512)
        atomicAdd(&bins[row[e] >> 8], 1);
    __syncthreads();
    for (int i = threadIdx.x; i < NBK; i += 512)
        M[i * 256 + blockIdx.x] = bins[i];
}

__global__ void k_scan1(const int* __restrict__ in, int* __restrict__ outx,
                        int* __restrict__ partials) {
    __shared__ int tmp[256];
    int t = threadIdx.x;
    int i = blockIdx.x * 256 + t;
    int v = (i < MLEN) ? in[i] : 0;
    tmp[t] = v;
    __syncthreads();
    #pragma unroll
    for (int off = 1; off < 256; off <<= 1) {
        int add = (t >= off) ? tmp[t - off] : 0;
        __syncthreads();
        tmp[t] += add;
        __syncthreads();
    }
    if (i < MLEN) outx[i] = tmp[t] - v;            // exclusive (within block)
    if (t == 255) partials[blockIdx.x] = tmp[255]; // block total
}

__global__ void k_scan2(int* __restrict__ partials) {
    __shared__ int tmp[512];
    int t = threadIdx.x;
    int v = (t < NBK) ? partials[t] : 0;
    tmp[t] = v;
    __syncthreads();
    #pragma unroll
    for (int off = 1; off < 512; off <<= 1) {
        int add = (t >= off) ? tmp[t - off] : 0;
        __syncthreads();
        tmp[t] += add;
        __syncthreads();
    }
    if (t < NBK) partials[t] = tmp[t] - v;         // exclusive
}

__global__ __launch_bounds__(512)
void k_bscatter(const int* __restrict__ row, const int* __restrict__ col,
                const float* __restrict__ ew, const int* __restrict__ Mscan,
                const int* __restrict__ partials,
                uint32* __restrict__ colw, uint8* __restrict__ rowlo) {
    __shared__ int cur[NBK];
    for (int i = threadIdx.x; i < NBK; i += 512)
        cur[i] = Mscan[i * 256 + blockIdx.x] + partials[i];
    __syncthreads();
    int start = blockIdx.x * EPB;
    int end = min(start + EPB, NE);
    for (int e = start + (int)threadIdx.x; e < end; e += 512) {
        int r = row[e];
        int wq = (int)(ew[e] * 32767.0f + 0.5f);
        wq = (wq > 32767) ? 32767 : wq;
        int p = atomicAdd(&cur[r >> 8], 1);
        colw[p]  = ((uint32)col[e] << 15) | (uint32)wq;
        rowlo[p] = (uint8)(r & 255);
    }
}

__global__ __launch_bounds__(256)
void k_build(const int* __restrict__ Mscan, const int* __restrict__ partials,
             const uint32* __restrict__ colw, const uint8* __restrict__ rowlo,
             uint32* __restrict__ edges, int* __restrict__ offsets) {
    __shared__ int bins[256];
    __shared__ int tmp[256];
    __shared__ int cur[256];
    int b = blockIdx.x;
    int t = threadIdx.x;
    int bstart = Mscan[b * 256] + partials[b];
    int bend   = (b == NBK - 1) ? NE : Mscan[(b + 1) * 256] + partials[b + 1];
    bins[t] = 0;
    __syncthreads();
    for (int p = bstart + t; p < bend; p += 256)
        atomicAdd(&bins[rowlo[p]], 1);
    __syncthreads();
    int v = bins[t];
    tmp[t] = v;
    __syncthreads();
    #pragma unroll
    for (int off = 1; off < 256; off <<= 1) {
        int add = (t >= off) ? tmp[t - off] : 0;
        __syncthreads();
        tmp[t] += add;
        __syncthreads();
    }
    int base = bstart + (tmp[t] - v);
    cur[t] = base;
    int rowid = b * 256 + t;
    if (rowid < NN) offsets[rowid] = base;
    if (b == 0 && t == 0) offsets[NN] = NE;
    __syncthreads();
    for (int p = bstart + t; p < bend; p += 256) {
        uint32 cw = colw[p];
        int dst = atomicAdd(&cur[rowlo[p]], 1);
        edges[dst] = cw;                 // block-private range: full lines
    }
}

// ---- W pre-pack: lane-ordered bf16 B-fragments for all 3 layers ---------

__global__ void k_packW(const float* __restrict__ selfk,
                        const float* __restrict__ neighk,
                        short8* __restrict__ wpack) {
    int tid = blockIdx.x * 256 + threadIdx.x;   // 3 layers * 16 frags * 64 lanes
    if (tid >= 3 * 16 * 64) return;
    int lane  = tid & 63;
    int frag  = (tid >> 6) & 15;
    int layer = tid >> 10;
    int g = frag >> 3;
    int t = (frag >> 2) & 1;
    int s = frag & 3;
    const float* W = (g ? neighk : selfk) + layer * 4096;
    int n = t * 32 + (lane & 31);
    int k0 = s * 16 + (lane >> 5) * 8;
    short8 v;
    #pragma unroll
    for (int j = 0; j < 8; j++) v[j] = (short)f2bf(W[(k0 + j) * 64 + n]);
    wpack[tid] = v;
}

// ---- MFMA GEMM (layer 1 only): hs = x@Ws + b, y = x@Wn ------------------

__global__ __launch_bounds__(256)
void gemm_mfma(const float* __restrict__ hf_, ushort16* __restrict__ hs,
               ushort16* __restrict__ y,
               const short8* __restrict__ wpack,
               const float* __restrict__ bias) {
    int lane  = threadIdx.x & 63;
    int wave  = threadIdx.x >> 6;
    int wid   = blockIdx.x * 4 + wave;
    int nwv   = gridDim.x * 4;
    int mrow  = lane & 31;
    int khalf = lane >> 5;
    int t     = wid & 1;

    short8 Wf[2][4];
    #pragma unroll
    for (int g = 0; g < 2; g++)
        #pragma unroll
        for (int s = 0; s < 4; s++)
            Wf[g][s] = wpack[(((g * 2 + t) * 4) + s) * 64 + lane];

    float bval = bias[t * 32 + mrow];

    for (int tile = wid >> 1; tile < NTILES; tile += nwv >> 1) {
        int n0 = tile * 32;
        const float* hf = hf_ + (n0 + mrow) * 64 + khalf * 8;
        short8 A[4];
        #pragma unroll
        for (int s = 0; s < 4; s++) {
            short8 a;
            #pragma unroll
            for (int j = 0; j < 8; j++) a[j] = (short)f2bf(hf[s * 16 + j]);
            A[s] = a;
        }

        f32x16 acc0, acc1;
        #pragma unroll
        for (int r = 0; r < 16; r++) { acc0[r] = 0.f; acc1[r] = 0.f; }

        #pragma unroll
        for (int s = 0; s < 4; s++) {
            acc0 = __builtin_amdgcn_mfma_f32_32x32x16_bf16(A[s], Wf[0][s], acc0, 0, 0, 0);
            acc1 = __builtin_amdgcn_mfma_f32_32x32x16_bf16(A[s], Wf[1][s], acc1, 0, 0, 0);
        }

        int colbase = t * 32 + mrow;
        #pragma unroll
        for (int r = 0; r < 16; r++) {
            int rw = (r & 3) + 8 * (r >> 2) + 4 * khalf;
            int n = n0 + rw;
            hs[n * DD + colbase] = f2bf(acc0[r] + bval);
            y [n * DD + colbase] = f2bf(acc1[r]);
        }
    }
}

// ---- Fused agg + next-layer GEMM ---------------------------------------
// Block = 32 nodes. Agg phase: 4 waves x 8 nodes (16-lane group per node,
// decoupled 16-deep gather pipeline). h packed bf16 into LDS (stride 36
// uints = 144 B). Gemm phase: wave = gsel*2 + t, 4 MFMA.

__global__ __launch_bounds__(256)
void agg_gemm(const uint2* __restrict__ hs2, const uint2* __restrict__ y2,
              ushort16* __restrict__ hs_out, ushort16* __restrict__ y_out,
              const int* __restrict__ offsets, const uint32* __restrict__ edges,
              const short8* __restrict__ wpack, const float* __restrict__ bias) {
    __shared__ uint32 sh[32 * 36];
    int lane = threadIdx.x & 63;
    int wave = threadIdx.x >> 6;
    int g  = lane >> 4;          // group 0..3
    int gb = lane & 48;          // group base lane
    int fl = lane & 15;          // feature quad
    int n0 = blockIdx.x * 32;

    #pragma unroll
    for (int q = 0; q < 2; q++) {
        int lrow = wave * 8 + q * 4 + g;     // 0..31
        int n = n0 + lrow;
        uint2 hv = hs2[n * 16 + fl];
        float a0 = bflo(hv.x), a1 = bfhi(hv.x), a2 = bflo(hv.y), a3 = bfhi(hv.y);
        agg_edges(a0, a1, a2, a3, offsets[n], offsets[n + 1], gb, fl, edges, y2);
        sh[lrow * 36 + fl * 2]     = pack2(fmaxf(a0, 0.f), fmaxf(a1, 0.f));
        sh[lrow * 36 + fl * 2 + 1] = pack2(fmaxf(a2, 0.f), fmaxf(a3, 0.f));
    }
    __syncthreads();

    // gemm phase
    int mrow  = lane & 31;
    int khalf = lane >> 5;
    int gsel  = wave >> 1;       // 0=self(hs) 1=neigh(y)
    int t     = wave & 1;        // col half

    short8 Wf[4];
    #pragma unroll
    for (int s = 0; s < 4; s++)
        Wf[s] = wpack[(((gsel * 2 + t) * 4) + s) * 64 + lane];

    short8 A[4];
    #pragma unroll
    for (int s = 0; s < 4; s++)
        A[s] = *(const short8*)&sh[mrow * 36 + s * 8 + khalf * 4];   // 16B, aligned

    f32x16 acc;
    #pragma unroll
    for (int r = 0; r < 16; r++) acc[r] = 0.f;
    #pragma unroll
    for (int s = 0; s < 4; s++)
        acc = __builtin_amdgcn_mfma_f32_32x32x16_bf16(A[s], Wf[s], acc, 0, 0, 0);

    float bval = gsel ? 0.f : bias[t * 32 + mrow];
    ushort16* dst = gsel ? y_out : hs_out;
    int colbase = t * 32 + mrow;
    #pragma unroll
    for (int r = 0; r < 16; r++) {
        int rw = (r & 3) + 8 * (r >> 2) + 4 * khalf;
        int n = n0 + rw;
        dst[n * DD + colbase] = f2bf(acc[r] + bval);
    }
}

// ---- Final aggregate: out = relu(hs[n] + sum_j w_j * y[col_j]), f32 ----

__global__ __launch_bounds__(256)
void agg_final(const uint2* __restrict__ hs2, const uint2* __restrict__ y2,
               float4* __restrict__ out, const int* __restrict__ offsets,
               const uint32* __restrict__ edges) {
    int lane = threadIdx.x & 63;
    int wave = threadIdx.x >> 6;
    int g  = lane >> 4;
    int gb = lane & 48;
    int fl = lane & 15;
    int n = (blockIdx.x * 4 + wave) * 4 + g;   // 6250*16 == NN exact

    uint2 hv = hs2[n * 16 + fl];
    float a0 = bflo(hv.x), a1 = bfhi(hv.x), a2 = bflo(hv.y), a3 = bfhi(hv.y);
    agg_edges(a0, a1, a2, a3, offsets[n], offsets[n + 1], gb, fl, edges, y2);
    out[n * 16 + fl] = make_float4(fmaxf(a0, 0.f), fmaxf(a1, 0.f),
                                   fmaxf(a2, 0.f), fmaxf(a3, 0.f));
}

// ---- launch -------------------------------------------------------------

extern "C" void kernel_launch(void* const* d_in, const int* in_sizes, int n_in,
                              void* d_out, int out_size, void* d_ws, size_t ws_size,
                              hipStream_t stream) {
    const float* x      = (const float*)d_in[0];
    const int*   ei     = (const int*)d_in[1];
    const float* ew     = (const float*)d_in[2];
    const float* selfk  = (const float*)d_in[3];
    const float* neighk = (const float*)d_in[4];
    const float* biases = (const float*)d_in[5];
    float* out = (float*)d_out;

    char* w = (char*)d_ws;
    ushort16* hsA   = (ushort16*)w; w += (size_t)NN * DD * sizeof(ushort16);
    ushort16* yA    = (ushort16*)w; w += (size_t)NN * DD * sizeof(ushort16);
    ushort16* hsB   = (ushort16*)w; w += (size_t)NN * DD * sizeof(ushort16);
    ushort16* yB    = (ushort16*)w; w += (size_t)NN * DD * sizeof(ushort16);
    uint32* edges   = (uint32*)w;   w += (size_t)NE * sizeof(uint32);
    uint32* colwB   = (uint32*)w;   w += (size_t)NE * sizeof(uint32);
    uint8*  rowlo   = (uint8*)w;    w += (size_t)NE * sizeof(uint8);
    w = (char*)(((size_t)w + 255) & ~(size_t)255);
    int*    M       = (int*)w;      w += (size_t)MLEN * sizeof(int);
    int*    Mscan   = (int*)w;      w += (size_t)MLEN * sizeof(int);
    int*    offsets = (int*)w;      w += (size_t)(NN + 1) * sizeof(int);
    int*    partials= (int*)w;      w += 512 * sizeof(int);
    short8* wpack   = (short8*)w;   w += (size_t)3 * 16 * 64 * sizeof(short8);

    const int* row = ei;
    const int* col = ei + NE;

    k_packW   <<<12, 256, 0, stream>>>(selfk, neighk, wpack);
    k_bcount  <<<256, 512, 0, stream>>>(row, M);
    k_scan1   <<<NBK, 256, 0, stream>>>(M, Mscan, partials);
    k_scan2   <<<1, 512, 0, stream>>>(partials);
    k_bscatter<<<256, 512, 0, stream>>>(row, col, ew, Mscan, partials, colwB, rowlo);
    k_build   <<<NBK, 256, 0, stream>>>(Mscan, partials, colwB, rowlo, edges, offsets);

    // layer 1 GEMM: x (f32) -> hsA, yA
    gemm_mfma<<<782, 256, 0, stream>>>(x, hsA, yA, wpack, biases);
    // agg(layer1) + GEMM(layer2): -> hsB, yB
    agg_gemm <<<NTILES, 256, 0, stream>>>((const uint2*)hsA, (const uint2*)yA,
                                          hsB, yB, offsets, edges,
                                          wpack + 1024, biases + 64);
    // agg(layer2) + GEMM(layer3): -> hsA, yA
    agg_gemm <<<NTILES, 256, 0, stream>>>((const uint2*)hsB, (const uint2*)yB,
                                          hsA, yA, offsets, edges,
                                          wpack + 2048, biases + 128);
    // final aggregate -> out (f32)
    agg_final<<<NN / 16, 256, 0, stream>>>((const uint2*)hsA, (const uint2*)yA,
                                           (float4*)out, offsets, edges);
}